// Round 1
// baseline (22247.128 us; speedup 1.0000x reference)
//
#include <hip/hip_runtime.h>

// Problem constants
constexpr int nB = 32, nT = 4096, nK = 256, nH = 512, nTP = 1024;

__device__ __forceinline__ float sigmoidf_(float x) { return 1.f / (1.f + expf(-x)); }

// ---------------- tokenizer ----------------

// sig[b][t] = mean_c x[b][t][c]; one 64-lane wave per row
__global__ __launch_bounds__(256) void k_mean(const float* __restrict__ x, float* __restrict__ sig) {
  int row = blockIdx.x * 4 + (threadIdx.x >> 6);
  int lane = threadIdx.x & 63;
  float v = x[(size_t)row * 64 + lane];
  #pragma unroll
  for (int off = 32; off > 0; off >>= 1) v += __shfl_down(v, off, 64);
  if (lane == 0) sig[row] = v * (1.0f / 64.0f);
}

// conv1: in=1 ch, out=64 ch, k=4, stride=2, SAME (pad_lo=1): h1[b][co][o], o in [0,2048)
__global__ __launch_bounds__(256) void k_conv1(const float* __restrict__ sig,
    const float* __restrict__ w1, const float* __restrict__ b1, float* __restrict__ h1) {
  int idx = blockIdx.x * 256 + threadIdx.x;
  int o = idx & 2047;
  int co = (idx >> 11) & 63;
  int b = idx >> 17;
  const float* s = sig + (size_t)b * nT;
  float acc = b1[co];
  int base = 2 * o - 1;
  #pragma unroll
  for (int j = 0; j < 4; j++) {
    int p = base + j;
    float sv = (p >= 0 && p < nT) ? s[p] : 0.f;
    acc = fmaf(w1[co * 4 + j], sv, acc);
  }
  h1[idx] = fmaxf(acc, 0.f);
}

// conv2: 64->64, k=4, s=2, SAME (pad_lo=1): h2[b][co][o], o in [0,1024)
__global__ __launch_bounds__(256) void k_conv2(const float* __restrict__ h1,
    const float* __restrict__ w2, const float* __restrict__ b2, float* __restrict__ h2) {
  int blk = blockIdx.x;
  int otile = blk & 3, co = (blk >> 2) & 63, b = blk >> 8;
  int o = otile * 256 + threadIdx.x;
  __shared__ float w[256];
  w[threadIdx.x] = w2[co * 256 + threadIdx.x];
  __syncthreads();
  const float* hin = h1 + (size_t)b * 64 * 2048;
  float acc = b2[co];
  int base = 2 * o - 1;
  for (int ci = 0; ci < 64; ci++) {
    const float* r = hin + ci * 2048;
    const float* wc = w + ci * 4;
    #pragma unroll
    for (int j = 0; j < 4; j++) {
      int p = base + j;
      float v = (p >= 0 && p < 2048) ? r[p] : 0.f;
      acc = fmaf(wc[j], v, acc);
    }
  }
  h2[((size_t)b * 64 + co) * 1024 + o] = fmaxf(acc, 0.f);
}

// conv3: 64->64, k=3, s=1, SAME (pad_lo=1): ze[b][d][o]
__global__ __launch_bounds__(256) void k_conv3(const float* __restrict__ h2,
    const float* __restrict__ w3, const float* __restrict__ b3, float* __restrict__ ze) {
  int blk = blockIdx.x;
  int otile = blk & 3, co = (blk >> 2) & 63, b = blk >> 8;
  int o = otile * 256 + threadIdx.x;
  __shared__ float w[192];
  if (threadIdx.x < 192) w[threadIdx.x] = w3[co * 192 + threadIdx.x];
  __syncthreads();
  const float* hin = h2 + (size_t)b * 64 * 1024;
  float acc = b3[co];
  for (int ci = 0; ci < 64; ci++) {
    const float* r = hin + ci * 1024;
    const float* wc = w + ci * 3;
    #pragma unroll
    for (int j = 0; j < 3; j++) {
      int p = o - 1 + j;
      float v = (p >= 0 && p < 1024) ? r[p] : 0.f;
      acc = fmaf(wc[j], v, acc);
    }
  }
  ze[((size_t)b * 64 + co) * 1024 + o] = acc;
}

// codebook norms ||e_k||^2
__global__ __launch_bounds__(256) void k_cbnorm(const float* __restrict__ cb, float* __restrict__ cbn) {
  int k = threadIdx.x;
  const float4* c4 = (const float4*)(cb + (size_t)k * 64);
  float acc = 0.f;
  #pragma unroll
  for (int q = 0; q < 16; q++) {
    float4 e = c4[q];
    acc = fmaf(e.x, e.x, fmaf(e.y, e.y, fmaf(e.z, e.z, fmaf(e.w, e.w, acc))));
  }
  cbn[k] = acc;
}

// VQ: argmin_k ||z - e_k||^2 (== argmin ||e||^2 - 2 z.e), then gather zq = e_idx
__global__ __launch_bounds__(256) void k_vq(const float* __restrict__ ze,
    const float* __restrict__ cb, const float* __restrict__ cbn, float* __restrict__ zq) {
  __shared__ float scb[nK * 64];   // 64 KB
  for (int i = threadIdx.x; i < nK * 64; i += 256) scb[i] = cb[i];
  __syncthreads();
  int g = blockIdx.x * 256 + threadIdx.x;   // token index
  int b = g >> 10, o = g & 1023;
  const float* zb = ze + (size_t)b * 64 * 1024 + o;
  float z[64];
  #pragma unroll
  for (int d = 0; d < 64; d++) z[d] = zb[(size_t)d * 1024];
  float best = 3.4e38f; int bi = 0;
  for (int k = 0; k < nK; k++) {
    const float4* ck = (const float4*)(scb + k * 64);
    float dot = 0.f;
    #pragma unroll
    for (int q = 0; q < 16; q++) {
      float4 c4 = ck[q];
      dot = fmaf(c4.x, z[4 * q + 0], dot);
      dot = fmaf(c4.y, z[4 * q + 1], dot);
      dot = fmaf(c4.z, z[4 * q + 2], dot);
      dot = fmaf(c4.w, z[4 * q + 3], dot);
    }
    float s = cbn[k] - 2.f * dot;
    if (s < best) { best = s; bi = k; }   // strict < keeps first index (matches jnp.argmin)
  }
  float4* zo4 = (float4*)(zq + (size_t)g * 64);
  const float4* cbest = (const float4*)(scb + bi * 64);
  #pragma unroll
  for (int q = 0; q < 16; q++) zo4[q] = cbest[q];
}

// ---------------- LSTM step ----------------
// State layouts are transposed: h*, c* stored as [dim][batch] ([512][32]).
// Threadblock: 256 = (b in 0..31) x (jj in 0..3) x (half in 0..1); block owns 4 hidden dims.
// Input vector v = concat(h_prev (512), x (IN_DIM)) staged chunkwise (128 rows) in LDS;
// half 0 computes even chunks, half 1 odd chunks, reduced via LDS at the end.

template<int IN_DIM>
__device__ __forceinline__ void lstm_block(float* smem, int jblk, int step,
    const float* __restrict__ zq, const float* __restrict__ xT,
    const float* __restrict__ wih, const float* __restrict__ whh, const float* __restrict__ bl,
    const float* __restrict__ hprevT, float* __restrict__ hnextT, float* __restrict__ cT)
{
  constexpr int VLEN = 512 + IN_DIM;
  constexpr int NCH = (VLEN + 127) >> 7;      // 5 (L0) or 8 (L1)
  constexpr int NPAIR = (NCH + 1) >> 1;       // 3 or 4
  float* buf0 = smem;          // 4096 floats
  float* buf1 = smem + 4096;   // 4096 floats
  float* part = smem + 8192;   // 512 floats
  const int tid = threadIdx.x;
  const int b = tid & 31, jj = (tid >> 5) & 3, half = tid >> 7;
  const int j = (jblk << 2) + jj;
  float a0 = 0.f, a1 = 0.f, a2 = 0.f, a3 = 0.f;

  for (int p = 0; p < NPAIR; p++) {
    __syncthreads();
    #pragma unroll
    for (int cc = 0; cc < 2; cc++) {
      int c = 2 * p + cc;
      if (c >= NCH) continue;
      float* dst = cc ? buf1 : buf0;
      int base = c << 7;
      if (base + 128 <= 512) {
        const float4* src = (const float4*)(hprevT + ((size_t)base << 5));
        float4* d4 = (float4*)dst;
        #pragma unroll
        for (int l = 0; l < 4; l++) d4[tid + l * 256] = src[tid + l * 256];
      } else if (IN_DIM == 512) {
        const float4* src = (const float4*)(xT + ((size_t)(base - 512) << 5));
        float4* d4 = (float4*)dst;
        #pragma unroll
        for (int l = 0; l < 4; l++) d4[tid + l * 256] = src[tid + l * 256];
      } else {
        // L0 input chunk: rows 512..575 hold zq, rest zero
        for (int l = tid; l < 4096; l += 256) {
          int row = base + (l >> 5), bb = l & 31;
          int dd = row - 512;
          float v = 0.f;
          if (dd < 64) v = zq[((size_t)bb * nTP + step) * 64 + dd];
          dst[l] = v;
        }
      }
    }
    __syncthreads();
    int c = 2 * p + half;
    if (c < NCH) {
      const float* vbuf = half ? buf1 : buf0;
      int base = c << 7;
      int n = VLEN - base; if (n > 128) n = 128;
      const float *wp0, *wp1, *wp2, *wp3;
      if (base < 512) {
        wp0 = whh + ((size_t)(0 * 512 + j)) * 512 + base;
        wp1 = whh + ((size_t)(1 * 512 + j)) * 512 + base;
        wp2 = whh + ((size_t)(2 * 512 + j)) * 512 + base;
        wp3 = whh + ((size_t)(3 * 512 + j)) * 512 + base;
      } else {
        int off = base - 512;
        wp0 = wih + ((size_t)(0 * 512 + j)) * IN_DIM + off;
        wp1 = wih + ((size_t)(1 * 512 + j)) * IN_DIM + off;
        wp2 = wih + ((size_t)(2 * 512 + j)) * IN_DIM + off;
        wp3 = wih + ((size_t)(3 * 512 + j)) * IN_DIM + off;
      }
      #pragma unroll 8
      for (int ii = 0; ii < n; ii += 4) {
        float4 w0 = *(const float4*)(wp0 + ii);
        float4 w1 = *(const float4*)(wp1 + ii);
        float4 w2 = *(const float4*)(wp2 + ii);
        float4 w3 = *(const float4*)(wp3 + ii);
        float v0 = vbuf[(ii + 0) * 32 + b];
        float v1 = vbuf[(ii + 1) * 32 + b];
        float v2 = vbuf[(ii + 2) * 32 + b];
        float v3 = vbuf[(ii + 3) * 32 + b];
        a0 = fmaf(w0.x, v0, fmaf(w0.y, v1, fmaf(w0.z, v2, fmaf(w0.w, v3, a0))));
        a1 = fmaf(w1.x, v0, fmaf(w1.y, v1, fmaf(w1.z, v2, fmaf(w1.w, v3, a1))));
        a2 = fmaf(w2.x, v0, fmaf(w2.y, v1, fmaf(w2.z, v2, fmaf(w2.w, v3, a2))));
        a3 = fmaf(w3.x, v0, fmaf(w3.y, v1, fmaf(w3.z, v2, fmaf(w3.w, v3, a3))));
      }
    }
  }
  __syncthreads();
  if (half) {
    float4* pp = (float4*)(part + (((jj << 5) + b) << 2));
    *pp = make_float4(a0, a1, a2, a3);
  }
  __syncthreads();
  if (!half) {
    const float4 q = *(const float4*)(part + (((jj << 5) + b) << 2));
    a0 += q.x + bl[j];
    a1 += q.y + bl[512 + j];
    a2 += q.z + bl[1024 + j];
    a3 += q.w + bl[1536 + j];
    float ig = sigmoidf_(a0);
    float fg = sigmoidf_(a1);
    float gg = tanhf(a2);
    float og = sigmoidf_(a3);
    int idx = (j << 5) + b;
    float cn = fmaf(fg, cT[idx], ig * gg);
    cT[idx] = cn;
    hnextT[idx] = og * tanhf(cn);
  }
}

// One launch per t: blocks 0-127 L0 step t, blocks 128-255 L1 step t-1, block 256 head step t-2.
__global__ __launch_bounds__(256) void k_step(int t,
    const float* __restrict__ zq,
    const float* __restrict__ wih0, const float* __restrict__ whh0, const float* __restrict__ bl0,
    const float* __restrict__ wih1, const float* __restrict__ whh1, const float* __restrict__ bl1,
    const float* __restrict__ wout, const float* __restrict__ bout,
    float* __restrict__ st, float* __restrict__ out)
{
  __shared__ float smem[2 * 4096 + 512];  // 34 KB
  float* h0T = st;             // [2][512][32]
  float* h1T = st + 32768;     // [2][512][32]
  float* c0T = st + 65536;     // [512][32]
  float* c1T = st + 81920;     // [512][32]
  int blk = blockIdx.x;
  if (blk < 128) {
    if (t >= nTP) return;
    const float* hprev = h0T + (t & 1) * 16384;
    float* hnext = h0T + ((t + 1) & 1) * 16384;
    lstm_block<64>(smem, blk, t, zq, nullptr, wih0, whh0, bl0, hprev, hnext, c0T);
  } else if (blk < 256) {
    if (t < 1 || t > nTP) return;
    int s = t - 1;
    const float* hprev = h1T + (s & 1) * 16384;
    float* hnext = h1T + ((s + 1) & 1) * 16384;
    const float* xT = h0T + (t & 1) * 16384;  // h0 step t-1
    lstm_block<512>(smem, blk - 128, s, nullptr, xT, wih1, whh1, bl1, hprev, hnext, c1T);
  } else {
    if (t < 2) return;
    int s2 = t - 2;
    const float* h1s = h1T + ((t - 1) & 1) * 16384;  // h1 step t-2
    int tid = threadIdx.x;
    if (tid < 192) {
      int oi = tid >> 5, b = tid & 31;
      float acc = bout[oi];
      const float* wr = wout + oi * 512;
      #pragma unroll 4
      for (int i = 0; i < 512; i += 4) {
        float4 w4 = *(const float4*)(wr + i);
        acc = fmaf(w4.x, h1s[(i + 0) * 32 + b], acc);
        acc = fmaf(w4.y, h1s[(i + 1) * 32 + b], acc);
        acc = fmaf(w4.z, h1s[(i + 2) * 32 + b], acc);
        acc = fmaf(w4.w, h1s[(i + 3) * 32 + b], acc);
      }
      out[((size_t)b * nTP + s2) * 6 + oi] = acc;
    }
  }
}

// ---------------- launch ----------------

extern "C" void kernel_launch(void* const* d_in, const int* in_sizes, int n_in,
                              void* d_out, int out_size, void* d_ws, size_t ws_size,
                              hipStream_t stream) {
  (void)in_sizes; (void)n_in; (void)out_size; (void)ws_size;
  const float* x    = (const float*)d_in[0];
  const float* w1   = (const float*)d_in[1];
  const float* b1   = (const float*)d_in[2];
  const float* w2   = (const float*)d_in[3];
  const float* b2   = (const float*)d_in[4];
  const float* w3   = (const float*)d_in[5];
  const float* b3   = (const float*)d_in[6];
  const float* cb   = (const float*)d_in[7];
  const float* wih0 = (const float*)d_in[8];
  const float* whh0 = (const float*)d_in[9];
  const float* bl0  = (const float*)d_in[10];
  const float* wih1 = (const float*)d_in[11];
  const float* whh1 = (const float*)d_in[12];
  const float* bl1  = (const float*)d_in[13];
  const float* wout = (const float*)d_in[14];
  const float* bout = (const float*)d_in[15];
  float* out = (float*)d_out;

  float* ws  = (float*)d_ws;
  float* sig = ws;                 // 131072
  float* h1c = sig + 131072;       // 4194304  [32][64][2048]
  float* h2c = h1c + 4194304;      // 2097152  [32][64][1024]
  float* ze  = h2c + 2097152;      // 2097152  [32][64][1024]
  float* zq  = ze  + 2097152;      // 2097152  [32*1024][64]
  float* cbn = zq  + 2097152;      // 256
  float* st  = cbn + 256;          // 98304 state floats (h0T[2], h1T[2], c0T, c1T)

  hipMemsetAsync(st, 0, 98304 * sizeof(float), stream);
  k_mean <<<32768, 256, 0, stream>>>(x, sig);
  k_conv1<<<16384, 256, 0, stream>>>(sig, w1, b1, h1c);
  k_conv2<<<8192, 256, 0, stream>>>(h1c, w2, b2, h2c);
  k_conv3<<<8192, 256, 0, stream>>>(h2c, w3, b3, ze);
  k_cbnorm<<<1, 256, 0, stream>>>(cb, cbn);
  k_vq   <<<128, 256, 0, stream>>>(ze, cb, cbn, zq);
  for (int t = 0; t <= nTP + 1; t++) {
    k_step<<<257, 256, 0, stream>>>(t, zq, wih0, whh0, bl0, wih1, whh1, bl1, wout, bout, st, out);
  }
}